// Round 1
// baseline (2773.509 us; speedup 1.0000x reference)
//
#include <hip/hip_runtime.h>

// MPNN regression, fp32 baseline.
// Key algebraic move: relu(h[src] @ W + b) == relu(h @ W + b)[src]  -> message
// GEMM runs on 10000 nodes, not 160000 edges (16x FLOP cut). Scatter-add fuses
// gather + atomic accumulation per edge.

// C[m,n] = act( sum_k A1[m,k]*W1[k,n] + (A2 ? sum_k A2[m,k]*W2[k,n] : 0) + bias[n] )
// A row-major [M,K*], W row-major [K*,N]. N % 64 == 0, K % 16 == 0.
__global__ __launch_bounds__(256) void gemm_f32(
    const float* __restrict__ A1, const float* __restrict__ W1, int K1,
    const float* __restrict__ A2, const float* __restrict__ W2, int K2,
    const float* __restrict__ bias, float* __restrict__ C,
    int M, int N, int do_relu)
{
    const int BM = 64, BN = 64, BK = 16;
    __shared__ float As[BK][BM + 4];  // +4 pad: keeps float4 LDS reads 16B-aligned, breaks conflicts
    __shared__ float Ws[BK][BN];

    const int tid = threadIdx.x;
    const int bm = blockIdx.x * BM;
    const int bn = blockIdx.y * BN;
    const int tm = tid >> 4;        // 0..15 -> 4 rows each
    const int tn = tid & 15;        // 0..15 -> 4 cols each

    // loader indexing
    const int la_row = tid >> 2;         // 0..63
    const int la_k4  = (tid & 3) << 2;   // 0,4,8,12
    const int lw_k   = tid >> 4;         // 0..15
    const int lw_n4  = (tid & 15) << 2;  // 0..60

    float acc[4][4] = {};

    for (int pass = 0; pass < 2; ++pass) {
        const float* __restrict__ A = pass ? A2 : A1;
        const float* __restrict__ W = pass ? W2 : W1;
        const int K = pass ? K2 : K1;
        if (A == nullptr) continue;  // block-uniform

        for (int k0 = 0; k0 < K; k0 += BK) {
            // stage A tile (transposed into LDS: As[k][m])
            const int arow = bm + la_row;
            float4 av = make_float4(0.f, 0.f, 0.f, 0.f);
            if (arow < M)
                av = *(const float4*)(A + (size_t)arow * K + k0 + la_k4);
            As[la_k4 + 0][la_row] = av.x;
            As[la_k4 + 1][la_row] = av.y;
            As[la_k4 + 2][la_row] = av.z;
            As[la_k4 + 3][la_row] = av.w;
            // stage W tile
            *(float4*)&Ws[lw_k][lw_n4] =
                *(const float4*)(W + (size_t)(k0 + lw_k) * N + bn + lw_n4);
            __syncthreads();

            #pragma unroll
            for (int k = 0; k < BK; ++k) {
                const float4 a = *(const float4*)&As[k][tm << 2];
                const float4 w = *(const float4*)&Ws[k][tn << 2];
                acc[0][0] += a.x * w.x; acc[0][1] += a.x * w.y;
                acc[0][2] += a.x * w.z; acc[0][3] += a.x * w.w;
                acc[1][0] += a.y * w.x; acc[1][1] += a.y * w.y;
                acc[1][2] += a.y * w.z; acc[1][3] += a.y * w.w;
                acc[2][0] += a.z * w.x; acc[2][1] += a.z * w.y;
                acc[2][2] += a.z * w.z; acc[2][3] += a.z * w.w;
                acc[3][0] += a.w * w.x; acc[3][1] += a.w * w.y;
                acc[3][2] += a.w * w.z; acc[3][3] += a.w * w.w;
            }
            __syncthreads();
        }
    }

    const int col = bn + (tn << 2);
    const float4 bv = *(const float4*)(bias + col);
    #pragma unroll
    for (int i = 0; i < 4; ++i) {
        const int row = bm + (tm << 2) + i;
        if (row >= M) continue;
        float4 o;
        o.x = acc[i][0] + bv.x;
        o.y = acc[i][1] + bv.y;
        o.z = acc[i][2] + bv.z;
        o.w = acc[i][3] + bv.w;
        if (do_relu) {
            o.x = fmaxf(o.x, 0.f); o.y = fmaxf(o.y, 0.f);
            o.z = fmaxf(o.z, 0.f); o.w = fmaxf(o.w, 0.f);
        }
        *(float4*)(C + (size_t)row * N + col) = o;
    }
}

// aggr[dst[e], :] += hmr[src[e], :]  for all edges. 128 threads (float4 lanes)
// per edge, 2 edges per 256-thread block.
__global__ __launch_bounds__(256) void scatter_add(
    const float* __restrict__ hmr, const int* __restrict__ eidx,
    float* __restrict__ aggr, int E)
{
    const int t = blockIdx.x * 256 + threadIdx.x;
    const int e = t >> 7;
    if (e >= E) return;
    const int c = (t & 127) << 2;
    const int s = eidx[e];       // src row (edge_index[0])
    const int d = eidx[E + e];   // dst row (edge_index[1])
    const float4 v = *(const float4*)(hmr + (size_t)s * 512 + c);
    float* p = aggr + (size_t)d * 512 + c;
    atomicAdd(p + 0, v.x);
    atomicAdd(p + 1, v.y);
    atomicAdd(p + 2, v.z);
    atomicAdd(p + 3, v.w);
}

// out[node] = dot(h[node,:512], W_out) + b_out. One wave per node.
__global__ __launch_bounds__(256) void out_dot(
    const float* __restrict__ h, const float* __restrict__ Wout,
    const float* __restrict__ bout, float* __restrict__ out, int M)
{
    const int gid = blockIdx.x * 256 + threadIdx.x;
    const int node = gid >> 6;   // wave-uniform
    const int lane = gid & 63;
    if (node >= M) return;
    const float* hp = h + (size_t)node * 512 + lane * 8;
    const float* wp = Wout + lane * 8;
    const float4 h0 = *(const float4*)(hp);
    const float4 h1 = *(const float4*)(hp + 4);
    const float4 w0 = *(const float4*)(wp);
    const float4 w1 = *(const float4*)(wp + 4);
    float s = h0.x * w0.x + h0.y * w0.y + h0.z * w0.z + h0.w * w0.w
            + h1.x * w1.x + h1.y * w1.y + h1.z * w1.z + h1.w * w1.w;
    #pragma unroll
    for (int off = 32; off > 0; off >>= 1)
        s += __shfl_down(s, off);
    if (lane == 0) out[node] = s + bout[0];
}

extern "C" void kernel_launch(void* const* d_in, const int* in_sizes, int n_in,
                              void* d_out, int out_size, void* d_ws, size_t ws_size,
                              hipStream_t stream)
{
    const float* x     = (const float*)d_in[0];
    const int*   eidx  = (const int*)  d_in[1];  // [2, E] flattened
    const float* W_in  = (const float*)d_in[2];
    const float* b_in  = (const float*)d_in[3];
    const float* msg_W = (const float*)d_in[4];  // [2, 512, 512]
    const float* msg_b = (const float*)d_in[5];  // [2, 512]
    const float* upd_W = (const float*)d_in[6];  // [2, 1024, 512]
    const float* upd_b = (const float*)d_in[7];  // [2, 512]
    const float* W_out = (const float*)d_in[8];  // [512, 1]
    const float* b_out = (const float*)d_in[9];

    const int IN = 256, H = 512, L = 2;
    const int M = in_sizes[0] / IN;   // 10000 nodes
    const int E = in_sizes[1] / 2;    // 160000 edges

    const size_t SZ = (size_t)M * H;  // floats per activation buffer
    float* B0 = (float*)d_ws;         // rotating buffers: h / hmr-then-hnext / aggr
    float* B1 = B0 + SZ;
    float* B2 = B1 + SZ;

    const dim3 blk(256);
    const dim3 gemmGrid((M + 63) / 64, H / 64);

    // h0 = relu(x @ W_in + b_in)
    gemm_f32<<<gemmGrid, blk, 0, stream>>>(x, W_in, IN, nullptr, nullptr, 0,
                                           b_in, B0, M, H, 1);

    float* h   = B0;
    float* tmp = B1;
    float* ag  = B2;
    for (int l = 0; l < L; ++l) {
        // hmr = relu(h @ msg_W[l] + msg_b[l])   (node-level; gather happens in scatter)
        gemm_f32<<<gemmGrid, blk, 0, stream>>>(h, msg_W + (size_t)l * H * H, H,
                                               nullptr, nullptr, 0,
                                               msg_b + (size_t)l * H, tmp, M, H, 1);
        // aggr = segment_sum(hmr[src], dst)
        hipMemsetAsync(ag, 0, SZ * sizeof(float), stream);
        scatter_add<<<dim3((E + 1) / 2), blk, 0, stream>>>(tmp, eidx, ag, E);
        // h' = relu(h @ upd_W[l][:512] + aggr @ upd_W[l][512:] + upd_b[l])
        const float* Wu = upd_W + (size_t)l * 2 * H * H;
        gemm_f32<<<gemmGrid, blk, 0, stream>>>(h, Wu, H,
                                               ag, Wu + (size_t)H * H, H,
                                               upd_b + (size_t)l * H, tmp, M, H, 1);
        float* sw = h; h = tmp; tmp = sw;  // rotate: tmp's old contents (hmr) are dead
    }

    // out = h @ W_out + b_out
    out_dot<<<dim3((M * 64 + 255) / 256), blk, 0, stream>>>(h, W_out, b_out,
                                                            (float*)d_out, M);
}

// Round 2
// 821.429 us; speedup vs baseline: 3.3764x; 3.3764x over previous
//
#include <hip/hip_runtime.h>

// MPNN regression, fp32. R2: atomic scatter-add replaced by per-call CSR build
// + deterministic per-node gather-sum (R1 counters: scatter WRITE_SIZE 1.28 GB
// vs 20 MB buffer -> atomic RMW line-eviction amplification was 2.1 ms of 2.77).

// ---------------- GEMM (unchanged from R1) ----------------
// C[m,n] = act( A1@W1 + (A2?A2@W2:0) + bias ), row-major, N%64==0, K%16==0.
__global__ __launch_bounds__(256) void gemm_f32(
    const float* __restrict__ A1, const float* __restrict__ W1, int K1,
    const float* __restrict__ A2, const float* __restrict__ W2, int K2,
    const float* __restrict__ bias, float* __restrict__ C,
    int M, int N, int do_relu)
{
    const int BM = 64, BN = 64, BK = 16;
    __shared__ float As[BK][BM + 4];
    __shared__ float Ws[BK][BN];

    const int tid = threadIdx.x;
    const int bm = blockIdx.x * BM;
    const int bn = blockIdx.y * BN;
    const int tm = tid >> 4;
    const int tn = tid & 15;

    const int la_row = tid >> 2;
    const int la_k4  = (tid & 3) << 2;
    const int lw_k   = tid >> 4;
    const int lw_n4  = (tid & 15) << 2;

    float acc[4][4] = {};

    for (int pass = 0; pass < 2; ++pass) {
        const float* __restrict__ A = pass ? A2 : A1;
        const float* __restrict__ W = pass ? W2 : W1;
        const int K = pass ? K2 : K1;
        if (A == nullptr) continue;

        for (int k0 = 0; k0 < K; k0 += BK) {
            const int arow = bm + la_row;
            float4 av = make_float4(0.f, 0.f, 0.f, 0.f);
            if (arow < M)
                av = *(const float4*)(A + (size_t)arow * K + k0 + la_k4);
            As[la_k4 + 0][la_row] = av.x;
            As[la_k4 + 1][la_row] = av.y;
            As[la_k4 + 2][la_row] = av.z;
            As[la_k4 + 3][la_row] = av.w;
            *(float4*)&Ws[lw_k][lw_n4] =
                *(const float4*)(W + (size_t)(k0 + lw_k) * N + bn + lw_n4);
            __syncthreads();

            #pragma unroll
            for (int k = 0; k < BK; ++k) {
                const float4 a = *(const float4*)&As[k][tm << 2];
                const float4 w = *(const float4*)&Ws[k][tn << 2];
                acc[0][0] += a.x * w.x; acc[0][1] += a.x * w.y;
                acc[0][2] += a.x * w.z; acc[0][3] += a.x * w.w;
                acc[1][0] += a.y * w.x; acc[1][1] += a.y * w.y;
                acc[1][2] += a.y * w.z; acc[1][3] += a.y * w.w;
                acc[2][0] += a.z * w.x; acc[2][1] += a.z * w.y;
                acc[2][2] += a.z * w.z; acc[2][3] += a.z * w.w;
                acc[3][0] += a.w * w.x; acc[3][1] += a.w * w.y;
                acc[3][2] += a.w * w.z; acc[3][3] += a.w * w.w;
            }
            __syncthreads();
        }
    }

    const int col = bn + (tn << 2);
    const float4 bv = *(const float4*)(bias + col);
    #pragma unroll
    for (int i = 0; i < 4; ++i) {
        const int row = bm + (tm << 2) + i;
        if (row >= M) continue;
        float4 o;
        o.x = acc[i][0] + bv.x;
        o.y = acc[i][1] + bv.y;
        o.z = acc[i][2] + bv.z;
        o.w = acc[i][3] + bv.w;
        if (do_relu) {
            o.x = fmaxf(o.x, 0.f); o.y = fmaxf(o.y, 0.f);
            o.z = fmaxf(o.z, 0.f); o.w = fmaxf(o.w, 0.f);
        }
        *(float4*)(C + (size_t)row * N + col) = o;
    }
}

// ---------------- CSR build (per call; reused across both layers) ----------------
__global__ __launch_bounds__(256) void count_deg(
    const int* __restrict__ eidx, int* __restrict__ deg, int E)
{
    const int e = blockIdx.x * 256 + threadIdx.x;
    if (e < E) atomicAdd(&deg[eidx[E + e]], 1);
}

// Single-block exclusive scan over n<=10240 degrees -> offs[0..n], cursor copy.
__global__ __launch_bounds__(256) void scan_offsets(
    const int* __restrict__ deg, int* __restrict__ offs,
    int* __restrict__ cursor, int n)
{
    __shared__ int part[256];
    const int tid = threadIdx.x;
    const int chunk = (n + 255) / 256;
    const int base = tid * chunk;
    int sum = 0;
    for (int i = 0; i < chunk; ++i) {
        const int idx = base + i;
        if (idx < n) sum += deg[idx];
    }
    part[tid] = sum;
    __syncthreads();
    for (int off = 1; off < 256; off <<= 1) {  // Hillis-Steele inclusive
        const int v = (tid >= off) ? part[tid - off] : 0;
        __syncthreads();
        part[tid] += v;
        __syncthreads();
    }
    int run = (tid == 0) ? 0 : part[tid - 1];
    for (int i = 0; i < chunk; ++i) {
        const int idx = base + i;
        if (idx < n) { offs[idx] = run; cursor[idx] = run; run += deg[idx]; }
    }
    if (tid == 255) offs[n] = part[255];
}

__global__ __launch_bounds__(256) void fill_csr(
    const int* __restrict__ eidx, int* __restrict__ cursor,
    int* __restrict__ srcs, int E)
{
    const int e = blockIdx.x * 256 + threadIdx.x;
    if (e < E) {
        const int pos = atomicAdd(&cursor[eidx[E + e]], 1);
        srcs[pos] = eidx[e];
    }
}

// ---------------- deterministic aggregation ----------------
// aggr[node,:] = sum over incoming edges of hmr[src,:]. 128 threads/node
// (float4 lanes over 512 cols), 2 nodes per 256-thread block. No atomics,
// aggr fully overwritten (no zero-init needed).
__global__ __launch_bounds__(256) void aggregate(
    const float* __restrict__ hmr, const int* __restrict__ offs,
    const int* __restrict__ srcs, float* __restrict__ aggr, int n)
{
    const int t = blockIdx.x * 256 + threadIdx.x;
    const int node = t >> 7;
    if (node >= n) return;
    const int c = (t & 127) << 2;
    const int beg = offs[node];
    const int end = offs[node + 1];
    float4 acc = make_float4(0.f, 0.f, 0.f, 0.f);
    for (int j = beg; j < end; ++j) {
        const int s = srcs[j];  // uniform across the 128-thread group -> broadcast
        const float4 v = *(const float4*)(hmr + (size_t)s * 512 + c);
        acc.x += v.x; acc.y += v.y; acc.z += v.z; acc.w += v.w;
    }
    *(float4*)(aggr + (size_t)node * 512 + c) = acc;
}

// ---------------- epilogue dot ----------------
__global__ __launch_bounds__(256) void out_dot(
    const float* __restrict__ h, const float* __restrict__ Wout,
    const float* __restrict__ bout, float* __restrict__ out, int M)
{
    const int gid = blockIdx.x * 256 + threadIdx.x;
    const int node = gid >> 6;
    const int lane = gid & 63;
    if (node >= M) return;
    const float* hp = h + (size_t)node * 512 + lane * 8;
    const float* wp = Wout + lane * 8;
    const float4 h0 = *(const float4*)(hp);
    const float4 h1 = *(const float4*)(hp + 4);
    const float4 w0 = *(const float4*)(wp);
    const float4 w1 = *(const float4*)(wp + 4);
    float s = h0.x * w0.x + h0.y * w0.y + h0.z * w0.z + h0.w * w0.w
            + h1.x * w1.x + h1.y * w1.y + h1.z * w1.z + h1.w * w1.w;
    #pragma unroll
    for (int off = 32; off > 0; off >>= 1)
        s += __shfl_down(s, off);
    if (lane == 0) out[node] = s + bout[0];
}

extern "C" void kernel_launch(void* const* d_in, const int* in_sizes, int n_in,
                              void* d_out, int out_size, void* d_ws, size_t ws_size,
                              hipStream_t stream)
{
    const float* x     = (const float*)d_in[0];
    const int*   eidx  = (const int*)  d_in[1];  // [2, E] flattened
    const float* W_in  = (const float*)d_in[2];
    const float* b_in  = (const float*)d_in[3];
    const float* msg_W = (const float*)d_in[4];  // [2, 512, 512]
    const float* msg_b = (const float*)d_in[5];  // [2, 512]
    const float* upd_W = (const float*)d_in[6];  // [2, 1024, 512]
    const float* upd_b = (const float*)d_in[7];  // [2, 512]
    const float* W_out = (const float*)d_in[8];  // [512, 1]
    const float* b_out = (const float*)d_in[9];

    const int IN = 256, H = 512, L = 2;
    const int M = in_sizes[0] / IN;   // 10000 nodes
    const int E = in_sizes[1] / 2;    // 160000 edges

    const size_t SZ = (size_t)M * H;
    float* B0 = (float*)d_ws;         // h / hmr-then-hnext / aggr rotating buffers
    float* B1 = B0 + SZ;
    float* B2 = B1 + SZ;
    int* deg    = (int*)(B2 + SZ);    // [M]
    int* offs   = deg + M;            // [M+1]
    int* cursor = offs + M + 1;       // [M]
    int* srcs   = cursor + M;         // [E]  src node id per dst-bucketed slot

    const dim3 blk(256);
    const dim3 gemmGrid((M + 63) / 64, H / 64);
    const dim3 edgeGrid((E + 255) / 256);
    const dim3 nodeGrid((M + 1) / 2);  // 2 nodes per block in aggregate

    // Build CSR (dst buckets) once per call; valid for both layers.
    hipMemsetAsync(deg, 0, (size_t)M * sizeof(int), stream);
    count_deg<<<edgeGrid, blk, 0, stream>>>(eidx, deg, E);
    scan_offsets<<<dim3(1), blk, 0, stream>>>(deg, offs, cursor, M);
    fill_csr<<<edgeGrid, blk, 0, stream>>>(eidx, cursor, srcs, E);

    // h0 = relu(x @ W_in + b_in)
    gemm_f32<<<gemmGrid, blk, 0, stream>>>(x, W_in, IN, nullptr, nullptr, 0,
                                           b_in, B0, M, H, 1);

    float* h   = B0;
    float* tmp = B1;
    float* ag  = B2;
    for (int l = 0; l < L; ++l) {
        // hmr = relu(h @ msg_W[l] + msg_b[l])  (node-level; gather is in aggregate)
        gemm_f32<<<gemmGrid, blk, 0, stream>>>(h, msg_W + (size_t)l * H * H, H,
                                               nullptr, nullptr, 0,
                                               msg_b + (size_t)l * H, tmp, M, H, 1);
        // aggr[d] = sum_{e: dst[e]==d} hmr[src[e]]
        aggregate<<<nodeGrid, blk, 0, stream>>>(tmp, offs, srcs, ag, M);
        // h' = relu(h @ upd_W[l][:512] + aggr @ upd_W[l][512:] + upd_b[l])
        const float* Wu = upd_W + (size_t)l * 2 * H * H;
        gemm_f32<<<gemmGrid, blk, 0, stream>>>(h, Wu, H,
                                               ag, Wu + (size_t)H * H, H,
                                               upd_b + (size_t)l * H, tmp, M, H, 1);
        float* sw = h; h = tmp; tmp = sw;
    }

    out_dot<<<dim3((M * 64 + 255) / 256), blk, 0, stream>>>(h, W_out, b_out,
                                                            (float*)d_out, M);
}

// Round 3
// 344.467 us; speedup vs baseline: 8.0516x; 2.3846x over previous
//
#include <hip/hip_runtime.h>

// MPNN regression. R3: GEMMs -> bf16 MFMA (16x16x32), 128x128 tiles,
// global_load_lds width-16 staging, weights transposed+cast to [N,K] bf16
// per call. Activations bf16, accumulation fp32 everywhere.

typedef __attribute__((ext_vector_type(8))) short short8;

#define ASYNC_COPY16(gptr, lptr)                                              \
    __builtin_amdgcn_global_load_lds(                                         \
        (const __attribute__((address_space(1))) void*)(gptr),                \
        (__attribute__((address_space(3))) void*)(lptr), 16, 0, 0)

__device__ __forceinline__ unsigned short f2b(float f) {  // RNE f32->bf16
    union { float f; unsigned u; } v; v.f = f;
    unsigned r = v.u + 0x7fff + ((v.u >> 16) & 1);
    return (unsigned short)(r >> 16);
}
__device__ __forceinline__ float b2f(unsigned b) {  // bf16 bits -> f32
    union { unsigned u; float f; } v; v.u = b << 16;
    return v.f;
}

// ---------------- bf16 MFMA GEMM ----------------
// C[M,512] = act( A1@W1 [+ A2@W2] + bias ), A row-major bf16 [M,K],
// Wt row-major bf16 [512, ldw] (= W transposed), k-offset pre-applied by
// caller. Block tile 128x128, 4 waves of 64x64, BK=32.
__global__ __launch_bounds__(256) void gemm_bf16(
    const unsigned short* __restrict__ A1, const unsigned short* __restrict__ W1t,
    int ldw1, int K1,
    const unsigned short* __restrict__ A2, const unsigned short* __restrict__ W2t,
    int ldw2, int K2,
    const float* __restrict__ bias, unsigned short* __restrict__ C,
    int M, int do_relu)
{
    __shared__ unsigned short As[4 * 128 * 8];  // [q][r][8k]  8 KB
    __shared__ unsigned short Bs[4 * 128 * 8];  // [q][n][8k]  8 KB

    const int tid  = threadIdx.x;
    const int wave = tid >> 6, lane = tid & 63;
    const int bm = blockIdx.x * 128, bn = blockIdx.y * 128;
    const int wr = (wave >> 1) * 64, wc = (wave & 1) * 64;
    const int m16 = lane & 15, quad = lane >> 4;

    typedef float float4v __attribute__((ext_vector_type(4)));
    float4v acc[4][4] = {};

    float bv[4];
    #pragma unroll
    for (int j = 0; j < 4; ++j) bv[j] = bias[bn + wc + j * 16 + m16];

    for (int pass = 0; pass < 2; ++pass) {
        const unsigned short* __restrict__ A  = pass ? A2 : A1;
        const unsigned short* __restrict__ Wt = pass ? W2t : W1t;
        const int ldw = pass ? ldw2 : ldw1;
        const int K   = pass ? K2 : K1;
        if (A == nullptr) continue;  // block-uniform

        for (int k0 = 0; k0 < K; k0 += 32) {
            // stage A and B tiles: linear chunk L = wave*128 + t*64 + lane,
            // q = L>>7, r = L&127; LDS dest = base + lane*16 (HW rule).
            #pragma unroll
            for (int t = 0; t < 2; ++t) {
                const int L = wave * 128 + t * 64 + lane;
                const int q = L >> 7, r = L & 127;
                int row = bm + r; row = row < M ? row : M - 1;
                const unsigned short* ga = A + (size_t)row * K + k0 + q * 8;
                ASYNC_COPY16(ga, (char*)As + (size_t)(wave * 128 + t * 64) * 16);
                const unsigned short* gb = Wt + (size_t)(bn + r) * ldw + k0 + q * 8;
                ASYNC_COPY16(gb, (char*)Bs + (size_t)(wave * 128 + t * 64) * 16);
            }
            __syncthreads();  // drains vmcnt (global_load_lds) + barrier

            short8 af[4], bf[4];
            #pragma unroll
            for (int i = 0; i < 4; ++i)
                af[i] = *(const short8*)&As[(size_t)(quad * 128 + wr + i * 16 + m16) * 8];
            #pragma unroll
            for (int j = 0; j < 4; ++j)
                bf[j] = *(const short8*)&Bs[(size_t)(quad * 128 + wc + j * 16 + m16) * 8];
            #pragma unroll
            for (int i = 0; i < 4; ++i)
                #pragma unroll
                for (int j = 0; j < 4; ++j)
                    acc[i][j] = __builtin_amdgcn_mfma_f32_16x16x32_bf16(
                        af[i], bf[j], acc[i][j], 0, 0, 0);
            __syncthreads();
        }
    }

    // epilogue: D layout col=lane&15, row=quad*4+reg
    #pragma unroll
    for (int i = 0; i < 4; ++i) {
        #pragma unroll
        for (int rg = 0; rg < 4; ++rg) {
            const int row = bm + wr + i * 16 + quad * 4 + rg;
            if (row >= M) continue;
            #pragma unroll
            for (int j = 0; j < 4; ++j) {
                float v = acc[i][j][rg] + bv[j];
                if (do_relu) v = fmaxf(v, 0.f);
                C[(size_t)row * 512 + bn + wc + j * 16 + m16] = f2b(v);
            }
        }
    }
}

// ---------------- weight transpose + cast: src f32 [R,C] -> dst bf16 [C,R] ----
__global__ __launch_bounds__(256) void transpose_cast(
    const float* __restrict__ src, unsigned short* __restrict__ dst, int R, int C)
{
    __shared__ float t[32][33];
    const int c0 = blockIdx.x * 32, r0 = blockIdx.y * 32;
    const int tx = threadIdx.x & 31, ty = threadIdx.x >> 5;  // ty 0..7
    #pragma unroll
    for (int i = 0; i < 32; i += 8) {
        const int r = r0 + ty + i, c = c0 + tx;
        t[ty + i][tx] = (r < R && c < C) ? src[(size_t)r * C + c] : 0.f;
    }
    __syncthreads();
    #pragma unroll
    for (int i = 0; i < 32; i += 8) {
        const int c = c0 + ty + i, r = r0 + tx;
        if (c < C && r < R) dst[(size_t)c * R + r] = f2b(t[tx][ty + i]);
    }
}

// ---------------- x cast f32 -> bf16 ----------------
__global__ __launch_bounds__(256) void cast_bf16(
    const float* __restrict__ s, unsigned short* __restrict__ d, int n4)
{
    const int i = blockIdx.x * 256 + threadIdx.x;
    if (i >= n4) return;
    const float4 v = *(const float4*)(s + (size_t)i * 4);
    ushort4 o = { f2b(v.x), f2b(v.y), f2b(v.z), f2b(v.w) };
    *(ushort4*)(d + (size_t)i * 4) = o;
}

// ---------------- CSR build ----------------
__global__ __launch_bounds__(256) void count_deg(
    const int* __restrict__ eidx, int* __restrict__ deg, int E)
{
    const int e = blockIdx.x * 256 + threadIdx.x;
    if (e < E) atomicAdd(&deg[eidx[E + e]], 1);
}

__global__ __launch_bounds__(256) void scan_offsets(
    const int* __restrict__ deg, int* __restrict__ offs,
    int* __restrict__ cursor, int n)
{
    __shared__ int part[256];
    const int tid = threadIdx.x;
    const int chunk = (n + 255) / 256;
    const int base = tid * chunk;
    int sum = 0;
    for (int i = 0; i < chunk; ++i) {
        const int idx = base + i;
        if (idx < n) sum += deg[idx];
    }
    part[tid] = sum;
    __syncthreads();
    for (int off = 1; off < 256; off <<= 1) {
        const int v = (tid >= off) ? part[tid - off] : 0;
        __syncthreads();
        part[tid] += v;
        __syncthreads();
    }
    int run = (tid == 0) ? 0 : part[tid - 1];
    for (int i = 0; i < chunk; ++i) {
        const int idx = base + i;
        if (idx < n) { offs[idx] = run; cursor[idx] = run; run += deg[idx]; }
    }
    if (tid == 255) offs[n] = part[255];
}

__global__ __launch_bounds__(256) void fill_csr(
    const int* __restrict__ eidx, int* __restrict__ cursor,
    int* __restrict__ srcs, int E)
{
    const int e = blockIdx.x * 256 + threadIdx.x;
    if (e < E) {
        const int pos = atomicAdd(&cursor[eidx[E + e]], 1);
        srcs[pos] = eidx[e];
    }
}

// ---------------- aggregation: aggr[d] = sum hmr[src] (bf16 in/out, f32 acc) --
// 64 lanes per node (8 bf16 = 16B per lane), 4 nodes per block.
__global__ __launch_bounds__(256) void aggregate_bf16(
    const unsigned short* __restrict__ hmr, const int* __restrict__ offs,
    const int* __restrict__ srcs, unsigned short* __restrict__ aggr, int n)
{
    const int t = blockIdx.x * 256 + threadIdx.x;
    const int node = t >> 6;
    if (node >= n) return;
    const int c8 = (t & 63) * 8;
    const int beg = offs[node], end = offs[node + 1];
    float a[8] = {};
    for (int j = beg; j < end; ++j) {
        const int s = srcs[j];  // uniform across the 64-lane group
        const uint4 v = *(const uint4*)(hmr + (size_t)s * 512 + c8);
        a[0] += b2f(v.x & 0xffff); a[1] += b2f(v.x >> 16);
        a[2] += b2f(v.y & 0xffff); a[3] += b2f(v.y >> 16);
        a[4] += b2f(v.z & 0xffff); a[5] += b2f(v.z >> 16);
        a[6] += b2f(v.w & 0xffff); a[7] += b2f(v.w >> 16);
    }
    uint4 o;
    o.x = f2b(a[0]) | ((unsigned)f2b(a[1]) << 16);
    o.y = f2b(a[2]) | ((unsigned)f2b(a[3]) << 16);
    o.z = f2b(a[4]) | ((unsigned)f2b(a[5]) << 16);
    o.w = f2b(a[6]) | ((unsigned)f2b(a[7]) << 16);
    *(uint4*)(aggr + (size_t)node * 512 + c8) = o;
}

// ---------------- epilogue dot: out = h @ W_out + b_out ----------------
__global__ __launch_bounds__(256) void out_dot(
    const unsigned short* __restrict__ h, const float* __restrict__ Wout,
    const float* __restrict__ bout, float* __restrict__ out, int M)
{
    const int gid = blockIdx.x * 256 + threadIdx.x;
    const int node = gid >> 6;
    const int lane = gid & 63;
    if (node >= M) return;
    const uint4 hv = *(const uint4*)(h + (size_t)node * 512 + lane * 8);
    const float4 w0 = *(const float4*)(Wout + lane * 8);
    const float4 w1 = *(const float4*)(Wout + lane * 8 + 4);
    float s = b2f(hv.x & 0xffff) * w0.x + b2f(hv.x >> 16) * w0.y
            + b2f(hv.y & 0xffff) * w0.z + b2f(hv.y >> 16) * w0.w
            + b2f(hv.z & 0xffff) * w1.x + b2f(hv.z >> 16) * w1.y
            + b2f(hv.w & 0xffff) * w1.z + b2f(hv.w >> 16) * w1.w;
    #pragma unroll
    for (int off = 32; off > 0; off >>= 1)
        s += __shfl_down(s, off);
    if (lane == 0) out[node] = s + bout[0];
}

extern "C" void kernel_launch(void* const* d_in, const int* in_sizes, int n_in,
                              void* d_out, int out_size, void* d_ws, size_t ws_size,
                              hipStream_t stream)
{
    const float* x     = (const float*)d_in[0];
    const int*   eidx  = (const int*)  d_in[1];
    const float* W_in  = (const float*)d_in[2];
    const float* b_in  = (const float*)d_in[3];
    const float* msg_W = (const float*)d_in[4];
    const float* msg_b = (const float*)d_in[5];
    const float* upd_W = (const float*)d_in[6];
    const float* upd_b = (const float*)d_in[7];
    const float* W_out = (const float*)d_in[8];
    const float* b_out = (const float*)d_in[9];

    const int IN = 256, H = 512, L = 2;
    const int M = in_sizes[0] / IN;   // 10000
    const int E = in_sizes[1] / 2;    // 160000

    // workspace layout (all bf16 chunks 16B-aligned)
    unsigned short* xb   = (unsigned short*)d_ws;            // [M*256]
    unsigned short* B0   = xb + (size_t)M * IN;              // [M*512]
    unsigned short* B1   = B0 + (size_t)M * H;
    unsigned short* B2   = B1 + (size_t)M * H;
    unsigned short* WinT = B2 + (size_t)M * H;               // [512,256]
    unsigned short* msgT = WinT + (size_t)H * IN;            // [2][512,512]
    unsigned short* updT = msgT + (size_t)L * H * H;         // [2][512,1024]
    int* deg    = (int*)(updT + (size_t)L * H * 2 * H);
    int* offs   = deg + M;
    int* cursor = offs + M + 1;
    int* srcs   = cursor + M;

    const dim3 blk(256);
    const dim3 gemmGrid((M + 127) / 128, H / 128);
    const dim3 edgeGrid((E + 255) / 256);

    // weight prep (independent of CSR / gemms until used)
    cast_bf16<<<dim3((M * IN / 4 + 255) / 256), blk, 0, stream>>>(x, xb, M * IN / 4);
    transpose_cast<<<dim3(H / 32, IN / 32), blk, 0, stream>>>(W_in, WinT, IN, H);
    for (int l = 0; l < L; ++l) {
        transpose_cast<<<dim3(H / 32, H / 32), blk, 0, stream>>>(
            msg_W + (size_t)l * H * H, msgT + (size_t)l * H * H, H, H);
        transpose_cast<<<dim3(H / 32, 2 * H / 32), blk, 0, stream>>>(
            upd_W + (size_t)l * 2 * H * H, updT + (size_t)l * H * 2 * H, 2 * H, H);
    }

    // CSR build (dst buckets), reused for both layers
    hipMemsetAsync(deg, 0, (size_t)M * sizeof(int), stream);
    count_deg<<<edgeGrid, blk, 0, stream>>>(eidx, deg, E);
    scan_offsets<<<dim3(1), blk, 0, stream>>>(deg, offs, cursor, M);
    fill_csr<<<edgeGrid, blk, 0, stream>>>(eidx, cursor, srcs, E);

    // h0 = relu(x @ W_in + b_in)
    gemm_bf16<<<gemmGrid, blk, 0, stream>>>(xb, WinT, IN, IN,
                                            nullptr, nullptr, 0, 0,
                                            b_in, B0, M, 1);

    unsigned short* h   = B0;
    unsigned short* tmp = B1;
    unsigned short* ag  = B2;
    for (int l = 0; l < L; ++l) {
        gemm_bf16<<<gemmGrid, blk, 0, stream>>>(
            h, msgT + (size_t)l * H * H, H, H,
            nullptr, nullptr, 0, 0,
            msg_b + (size_t)l * H, tmp, M, 1);
        aggregate_bf16<<<dim3((M * 64 + 255) / 256), blk, 0, stream>>>(
            tmp, offs, srcs, ag, M);
        const unsigned short* Wu = updT + (size_t)l * H * 2 * H;  // [512,1024]
        gemm_bf16<<<gemmGrid, blk, 0, stream>>>(
            h, Wu, 2 * H, H,
            ag, Wu + H, 2 * H, H,     // k-offset 512 into each row
            upd_b + (size_t)l * H, tmp, M, 1);
        unsigned short* sw = h; h = tmp; tmp = sw;
    }

    out_dot<<<dim3((M * 64 + 255) / 256), blk, 0, stream>>>(
        h, W_out, b_out, (float*)d_out, M);
}

// Round 4
// 334.930 us; speedup vs baseline: 8.2809x; 1.0285x over previous
//
#include <hip/hip_runtime.h>

// MPNN regression. R4: fp16 MFMA (16x16x32_f16) for 8x accuracy headroom over
// bf16 (absmax was 1.5 vs 1.57 threshold), BK=64 K-loop (half the barrier
// drains), fused prep kernel (x cast + 5 weight transposes + deg zeroing in
// one launch). fp32 accumulation everywhere.

typedef _Float16 half8 __attribute__((ext_vector_type(8)));
typedef float float4v __attribute__((ext_vector_type(4)));

#define ASYNC_COPY16(gptr, lptr)                                              \
    __builtin_amdgcn_global_load_lds(                                         \
        (const __attribute__((address_space(1))) void*)(gptr),                \
        (__attribute__((address_space(3))) void*)(lptr), 16, 0, 0)

// ---------------- fp16 MFMA GEMM ----------------
// C[M,512] = act( A1@W1 [+ A2@W2] + bias ), A row-major fp16 [M,K],
// Wt row-major fp16 [512, ldw] (W transposed; k-offset pre-applied by caller).
// Block tile 128x128, 4 waves of 64x64, BK=64.
__global__ __launch_bounds__(256) void gemm_f16(
    const _Float16* __restrict__ A1, const _Float16* __restrict__ W1t,
    int ldw1, int K1,
    const _Float16* __restrict__ A2, const _Float16* __restrict__ W2t,
    int ldw2, int K2,
    const float* __restrict__ bias, _Float16* __restrict__ C,
    int M, int do_relu)
{
    // [chunk 0..7][row 0..127][8 halves]; chunk = (k_sub<<2)|quad, 16 KB each
    __shared__ _Float16 As[8 * 128 * 8];
    __shared__ _Float16 Bs[8 * 128 * 8];

    const int tid  = threadIdx.x;
    const int wave = tid >> 6, lane = tid & 63;
    const int bm = blockIdx.x * 128, bn = blockIdx.y * 128;
    const int wr = (wave >> 1) * 64, wc = (wave & 1) * 64;
    const int m16 = lane & 15, quad = lane >> 4;

    float4v acc[4][4] = {};

    float bv[4];
    #pragma unroll
    for (int j = 0; j < 4; ++j) bv[j] = bias[bn + wc + j * 16 + m16];

    for (int pass = 0; pass < 2; ++pass) {
        const _Float16* __restrict__ A  = pass ? A2 : A1;
        const _Float16* __restrict__ Wt = pass ? W2t : W1t;
        const int ldw = pass ? ldw2 : ldw1;
        const int K   = pass ? K2 : K1;
        if (A == nullptr) continue;  // block-uniform

        for (int k0 = 0; k0 < K; k0 += 64) {
            // stage 128 rows x 64 k of A and B: 4 async16 each per thread.
            // linear slot L = t*256 + wave*64 + lane; chunk = L>>7, row = L&127;
            // LDS dest = wave-uniform base + lane*16 (HW rule).
            #pragma unroll
            for (int t = 0; t < 4; ++t) {
                const int L = t * 256 + wave * 64 + lane;
                const int ch = L >> 7, r = L & 127;
                int row = bm + r; row = row < M ? row : M - 1;
                ASYNC_COPY16(A + (size_t)row * K + k0 + ch * 8,
                             (char*)As + (size_t)(t * 256 + wave * 64) * 16);
                ASYNC_COPY16(Wt + (size_t)(bn + r) * ldw + k0 + ch * 8,
                             (char*)Bs + (size_t)(t * 256 + wave * 64) * 16);
            }
            __syncthreads();  // drains vmcnt (global_load_lds) + barrier

            #pragma unroll
            for (int c = 0; c < 2; ++c) {
                half8 af[4], bf[4];
                #pragma unroll
                for (int i = 0; i < 4; ++i)
                    af[i] = *(const half8*)
                        &As[(size_t)((c * 4 + quad) * 128 + wr + i * 16 + m16) * 8];
                #pragma unroll
                for (int j = 0; j < 4; ++j)
                    bf[j] = *(const half8*)
                        &Bs[(size_t)((c * 4 + quad) * 128 + wc + j * 16 + m16) * 8];
                #pragma unroll
                for (int i = 0; i < 4; ++i)
                    #pragma unroll
                    for (int j = 0; j < 4; ++j)
                        acc[i][j] = __builtin_amdgcn_mfma_f32_16x16x32_f16(
                            af[i], bf[j], acc[i][j], 0, 0, 0);
            }
            __syncthreads();
        }
    }

    // epilogue: D layout col=lane&15, row=quad*4+reg
    #pragma unroll
    for (int i = 0; i < 4; ++i) {
        #pragma unroll
        for (int rg = 0; rg < 4; ++rg) {
            const int row = bm + wr + i * 16 + quad * 4 + rg;
            if (row >= M) continue;
            #pragma unroll
            for (int j = 0; j < 4; ++j) {
                float v = acc[i][j][rg] + bv[j];
                if (do_relu) v = fmaxf(v, 0.f);
                C[(size_t)row * 512 + bn + wc + j * 16 + m16] = (_Float16)v;
            }
        }
    }
}

// ---------------- fused prep: weight transposes + x cast + deg zero ----------
// All weight matrices are [R,512] f32 -> dst [512,R] fp16. Tile = 32x32.
// blocks [0,1664): transpose; [1664, 1664+castBlocks): x cast; then deg zero.
__global__ __launch_bounds__(256) void prep(
    const float* __restrict__ W_in,  _Float16* __restrict__ WinT,
    const float* __restrict__ msg_W, _Float16* __restrict__ msgT,
    const float* __restrict__ upd_W, _Float16* __restrict__ updT,
    const float* __restrict__ x,     _Float16* __restrict__ xb,
    int* __restrict__ deg, int n4, int M)
{
    const int b = blockIdx.x;
    const int tid = threadIdx.x;
    if (b < 1664) {
        const float* src; _Float16* dst; int R; int tb;
        if (b < 128)       { src = W_in;              dst = WinT;              R = 256;  tb = b; }
        else if (b < 384)  { src = msg_W;             dst = msgT;              R = 512;  tb = b - 128; }
        else if (b < 640)  { src = msg_W + 512 * 512; dst = msgT + 512 * 512;  R = 512;  tb = b - 384; }
        else if (b < 1152) { src = upd_W;             dst = updT;              R = 1024; tb = b - 640; }
        else               { src = upd_W + 1024 * 512; dst = updT + 1024 * 512; R = 1024; tb = b - 1152; }
        const int rtiles = R >> 5;
        const int r0 = (tb % rtiles) * 32;
        const int c0 = (tb / rtiles) * 32;
        __shared__ float t[32][33];
        const int tx = tid & 31, ty = tid >> 5;  // ty 0..7
        #pragma unroll
        for (int i = 0; i < 32; i += 8)
            t[ty + i][tx] = src[(size_t)(r0 + ty + i) * 512 + c0 + tx];
        __syncthreads();
        #pragma unroll
        for (int i = 0; i < 32; i += 8)
            dst[(size_t)(c0 + ty + i) * R + r0 + tx] = (_Float16)t[tx][ty + i];
    } else {
        const int cb = b - 1664;
        const int i = cb * 256 + tid;
        if (i < n4) {
            const float4 v = *(const float4*)(x + (size_t)i * 4);
            half8 o;  // only low 4 used? pack 4 halves via ushort4 store
            ushort4 s;
            union { _Float16 h; unsigned short u; } cv;
            cv.h = (_Float16)v.x; s.x = cv.u;
            cv.h = (_Float16)v.y; s.y = cv.u;
            cv.h = (_Float16)v.z; s.z = cv.u;
            cv.h = (_Float16)v.w; s.w = cv.u;
            *(ushort4*)((unsigned short*)xb + (size_t)i * 4) = s;
            (void)o;
        }
        const int castBlocks = (n4 + 255) / 256;
        if (cb >= castBlocks) {
            const int zi = (cb - castBlocks) * 256 + tid;
            if (zi < M) deg[zi] = 0;
        }
    }
}

// ---------------- CSR build ----------------
__global__ __launch_bounds__(256) void count_deg(
    const int* __restrict__ eidx, int* __restrict__ deg, int E)
{
    const int e = blockIdx.x * 256 + threadIdx.x;
    if (e < E) atomicAdd(&deg[eidx[E + e]], 1);
}

__global__ __launch_bounds__(256) void scan_offsets(
    const int* __restrict__ deg, int* __restrict__ offs,
    int* __restrict__ cursor, int n)
{
    __shared__ int part[256];
    const int tid = threadIdx.x;
    const int chunk = (n + 255) / 256;
    const int base = tid * chunk;
    int sum = 0;
    for (int i = 0; i < chunk; ++i) {
        const int idx = base + i;
        if (idx < n) sum += deg[idx];
    }
    part[tid] = sum;
    __syncthreads();
    for (int off = 1; off < 256; off <<= 1) {
        const int v = (tid >= off) ? part[tid - off] : 0;
        __syncthreads();
        part[tid] += v;
        __syncthreads();
    }
    int run = (tid == 0) ? 0 : part[tid - 1];
    for (int i = 0; i < chunk; ++i) {
        const int idx = base + i;
        if (idx < n) { offs[idx] = run; cursor[idx] = run; run += deg[idx]; }
    }
    if (tid == 255) offs[n] = part[255];
}

__global__ __launch_bounds__(256) void fill_csr(
    const int* __restrict__ eidx, int* __restrict__ cursor,
    int* __restrict__ srcs, int E)
{
    const int e = blockIdx.x * 256 + threadIdx.x;
    if (e < E) {
        const int pos = atomicAdd(&cursor[eidx[E + e]], 1);
        srcs[pos] = eidx[e];
    }
}

// ---------------- aggregation: aggr[d] = sum hmr[src] (fp16 in/out, f32 acc) --
// 64 lanes per node (8 halves = 16B per lane), unroll-2 for 2 loads in flight.
__global__ __launch_bounds__(256) void aggregate_f16(
    const _Float16* __restrict__ hmr, const int* __restrict__ offs,
    const int* __restrict__ srcs, _Float16* __restrict__ aggr, int n)
{
    const int t = blockIdx.x * 256 + threadIdx.x;
    const int node = t >> 6;
    if (node >= n) return;
    const int c8 = (t & 63) * 8;
    const int beg = offs[node], end = offs[node + 1];
    float a[8] = {};
    int j = beg;
    for (; j + 1 < end; j += 2) {
        const half8 v0 = *(const half8*)(hmr + (size_t)srcs[j]     * 512 + c8);
        const half8 v1 = *(const half8*)(hmr + (size_t)srcs[j + 1] * 512 + c8);
        #pragma unroll
        for (int i = 0; i < 8; ++i) a[i] += (float)v0[i] + (float)v1[i];
    }
    if (j < end) {
        const half8 v = *(const half8*)(hmr + (size_t)srcs[j] * 512 + c8);
        #pragma unroll
        for (int i = 0; i < 8; ++i) a[i] += (float)v[i];
    }
    half8 o;
    #pragma unroll
    for (int i = 0; i < 8; ++i) o[i] = (_Float16)a[i];
    *(half8*)(aggr + (size_t)node * 512 + c8) = o;
}

// ---------------- epilogue dot: out = h @ W_out + b_out ----------------
__global__ __launch_bounds__(256) void out_dot(
    const _Float16* __restrict__ h, const float* __restrict__ Wout,
    const float* __restrict__ bout, float* __restrict__ out, int M)
{
    const int gid = blockIdx.x * 256 + threadIdx.x;
    const int node = gid >> 6;
    const int lane = gid & 63;
    if (node >= M) return;
    const half8 hv = *(const half8*)(h + (size_t)node * 512 + lane * 8);
    const float4 w0 = *(const float4*)(Wout + lane * 8);
    const float4 w1 = *(const float4*)(Wout + lane * 8 + 4);
    float s = (float)hv[0] * w0.x + (float)hv[1] * w0.y
            + (float)hv[2] * w0.z + (float)hv[3] * w0.w
            + (float)hv[4] * w1.x + (float)hv[5] * w1.y
            + (float)hv[6] * w1.z + (float)hv[7] * w1.w;
    #pragma unroll
    for (int off = 32; off > 0; off >>= 1)
        s += __shfl_down(s, off);
    if (lane == 0) out[node] = s + bout[0];
}

extern "C" void kernel_launch(void* const* d_in, const int* in_sizes, int n_in,
                              void* d_out, int out_size, void* d_ws, size_t ws_size,
                              hipStream_t stream)
{
    const float* x     = (const float*)d_in[0];
    const int*   eidx  = (const int*)  d_in[1];
    const float* W_in  = (const float*)d_in[2];
    const float* b_in  = (const float*)d_in[3];
    const float* msg_W = (const float*)d_in[4];
    const float* msg_b = (const float*)d_in[5];
    const float* upd_W = (const float*)d_in[6];
    const float* upd_b = (const float*)d_in[7];
    const float* W_out = (const float*)d_in[8];
    const float* b_out = (const float*)d_in[9];

    const int IN = 256, H = 512, L = 2;
    const int M = in_sizes[0] / IN;   // 10000
    const int E = in_sizes[1] / 2;    // 160000

    // workspace layout (fp16 chunks all 16B-aligned)
    _Float16* xb   = (_Float16*)d_ws;                 // [M*256]
    _Float16* B0   = xb + (size_t)M * IN;             // [M*512]
    _Float16* B1   = B0 + (size_t)M * H;
    _Float16* B2   = B1 + (size_t)M * H;
    _Float16* WinT = B2 + (size_t)M * H;              // [512,256]
    _Float16* msgT = WinT + (size_t)H * IN;           // [2][512,512]
    _Float16* updT = msgT + (size_t)L * H * H;        // [2][512,1024]
    int* deg    = (int*)(updT + (size_t)L * H * 2 * H);
    int* offs   = deg + M;
    int* cursor = offs + M + 1;
    int* srcs   = cursor + M;

    const dim3 blk(256);
    const dim3 gemmGrid((M + 127) / 128, H / 128);
    const dim3 edgeGrid((E + 255) / 256);

    // one fused prep launch: 5 transposes + x cast + deg zero
    const int n4 = M * IN / 4;
    const int castBlocks = (n4 + 255) / 256;
    const int zeroBlocks = (M + 255) / 256;
    prep<<<dim3(1664 + castBlocks + zeroBlocks), blk, 0, stream>>>(
        W_in, WinT, msg_W, msgT, upd_W, updT, x, xb, deg, n4, M);

    // CSR build (dst buckets), reused for both layers
    count_deg<<<edgeGrid, blk, 0, stream>>>(eidx, deg, E);
    scan_offsets<<<dim3(1), blk, 0, stream>>>(deg, offs, cursor, M);
    fill_csr<<<edgeGrid, blk, 0, stream>>>(eidx, cursor, srcs, E);

    // h0 = relu(x @ W_in + b_in)
    gemm_f16<<<gemmGrid, blk, 0, stream>>>(xb, WinT, IN, IN,
                                           nullptr, nullptr, 0, 0,
                                           b_in, B0, M, 1);

    _Float16* h   = B0;
    _Float16* tmp = B1;
    _Float16* ag  = B2;
    for (int l = 0; l < L; ++l) {
        gemm_f16<<<gemmGrid, blk, 0, stream>>>(
            h, msgT + (size_t)l * H * H, H, H,
            nullptr, nullptr, 0, 0,
            msg_b + (size_t)l * H, tmp, M, 1);
        aggregate_f16<<<dim3((M * 64 + 255) / 256), blk, 0, stream>>>(
            tmp, offs, srcs, ag, M);
        const _Float16* Wu = updT + (size_t)l * H * 2 * H;  // [512,1024]
        gemm_f16<<<gemmGrid, blk, 0, stream>>>(
            h, Wu, 2 * H, H,
            ag, Wu + H, 2 * H, H,      // k-offset 512 within each row
            upd_b + (size_t)l * H, tmp, M, 1);
        _Float16* sw = h; h = tmp; tmp = sw;
    }

    out_dot<<<dim3((M * 64 + 255) / 256), blk, 0, stream>>>(
        h, W_out, b_out, (float*)d_out, M);
}